// Round 9
// baseline (85.462 us; speedup 1.0000x reference)
//
#include <hip/hip_runtime.h>

typedef __bf16 bf16x8 __attribute__((ext_vector_type(8)));
typedef float f32x4 __attribute__((ext_vector_type(4)));

static __device__ __forceinline__ f32x4 mfma16(bf16x8 a, bf16x8 b, f32x4 c) {
  return __builtin_amdgcn_mfma_f32_16x16x32_bf16(a, b, c, 0, 0, 0);
}
static __device__ __forceinline__ unsigned cvtpk(float lo, float hi) {
  unsigned r;
  asm("v_cvt_pk_bf16_f32 %0, %1, %2" : "=v"(r) : "v"(lo), "v"(hi));
  return r;
}

// ---- pre-pass 1: K fp32 -> bf16 packed in MFMA-fragment order ----
// KS[bh][ch][t2*2+br][g][c][j] : 1KB blocks; a wave's fragment load is one
// contiguous 1KB region (lane (c,g) reads 16B at g*256 + c*16).
__global__ __launch_bounds__(256)
void kpack(const float* __restrict__ K, __bf16* __restrict__ KS) {
  const int bh = blockIdx.x >> 6, ch = blockIdx.x & 63;
  const int t = threadIdx.x;
  const int t2 = t >> 7, br = (t >> 6) & 1, g = (t >> 4) & 3, c = t & 15;
  const float* src = K + ((size_t)bh * 2048 + ch * 32 + t2 * 16 + c) * 64 + br * 32 + g * 8;
  float4 f0 = *(const float4*)src;
  float4 f1 = *(const float4*)(src + 4);
  bf16x8 v;
  v[0] = (__bf16)f0.x; v[1] = (__bf16)f0.y; v[2] = (__bf16)f0.z; v[3] = (__bf16)f0.w;
  v[4] = (__bf16)f1.x; v[5] = (__bf16)f1.y; v[6] = (__bf16)f1.z; v[7] = (__bf16)f1.w;
  *(bf16x8*)(KS + (size_t)bh * 131072 + ch * 2048 + t * 8) = v;   // fully coalesced
}

// ---- pre-pass 2: V fp32 [bh][s][64] -> V^T bf16 packed fragment order ----
// VS[bh][ch][dt][g][c][j] = V[bh][ch*32+8g+j][16dt+c] : 1KB blocks.
__global__ __launch_bounds__(256)
void vpack(const float* __restrict__ V, __bf16* __restrict__ VS) {
  __shared__ float tile[64][65];
  const int bh = blockIdx.x >> 5;
  const int s0 = (blockIdx.x & 31) * 64;
  const int t = threadIdx.x;
  const float* Vb = V + (size_t)bh * 2048 * 64;
#pragma unroll
  for (int i = 0; i < 4; ++i) {
    const int r = i * 16 + (t >> 4);
    const int c4 = (t & 15) * 4;
    float4 v = *(const float4*)(Vb + (s0 + r) * 64 + c4);
    tile[r][c4] = v.x; tile[r][c4 + 1] = v.y;
    tile[r][c4 + 2] = v.z; tile[r][c4 + 3] = v.w;
  }
  __syncthreads();
  const int dt = t >> 6, g = (t >> 4) & 3, c = t & 15;
#pragma unroll
  for (int hh = 0; hh < 2; ++hh) {
    const int ch = (blockIdx.x & 31) * 2 + hh;
    bf16x8 v;
#pragma unroll
    for (int j = 0; j < 8; ++j) v[j] = (__bf16)tile[hh * 32 + 8 * g + j][16 * dt + c];
    *(bf16x8*)(VS + (size_t)bh * 131072 + ch * 2048 + dt * 512 + g * 128 + c * 8) = v;
  }
}

// ---- main: 4-wave kv-split swapped-operand flash diff-attention ----
// R9 vs R8 (replay-nondeterministic): same kv-split occupancy idea, but
// 256-thr blocks (2 ws x 2 h), NO smem union (three typed arrays), and
// launch_bounds(256,3) so nothing spills (VGPR cap ~170 >= ~163 demand).
// Step body is byte-identical to the verified R5/R7 kernels; merge is the
// audited publish/barrier/consume pattern. 32 q rows/wave, 32 steps/wave.
__global__ __launch_bounds__(256, 3)
void diffattn(const float* __restrict__ Q, const __bf16* __restrict__ KS,
              const __bf16* __restrict__ VS, const float* __restrict__ LP,
              float* __restrict__ OUT) {
  constexpr int S = 2048, D = 64;
  constexpr float QSCALE = 0.17677669529663687f * 1.4426950408889634f;

  __shared__ __align__(16) uint2 Pl[4][2][2][16][10];   // [w][qt][br][q][kv] 20480B
  __shared__ __align__(16) f32x4 Macc[2][2][4][64];     // [ws][br][dt][lane] 16384B
  __shared__ float Mrs[2][2][64];                       // [ws][br][lane]      1024B

  const int raw = blockIdx.x;
  const int wg  = (raw & 7) * 128 + (raw >> 3);  // XCD swizzle (1024 % 8 == 0)
  const int bh  = wg >> 5;
  const int qb  = wg & 31;
  const float lam = LP[bh & 15];

  const int tid  = threadIdx.x;
  const int w    = tid >> 6;
  const int ws   = w & 1;        // q-subtile
  const int h    = w >> 1;       // kv-half
  const int lane = tid & 63;
  const int c    = lane & 15;
  const int g    = lane >> 4;
  const int q0   = qb * 64 + ws * 32;            // 32 q rows per wave

  const float*  Qb    = Q  + (size_t)bh * S * D;
  const __bf16* Kbase = KS + (size_t)bh * 131072 + h * 65536 + g * 128 + c * 8;
  const __bf16* Vbase = VS + (size_t)bh * 131072 + h * 65536 + g * 128 + c * 8;

  // Q fragments: bq[qt][br], B[k = br*32+8g+j][n = c]
  bf16x8 bq[2][2];
#pragma unroll
  for (int qt = 0; qt < 2; ++qt)
#pragma unroll
    for (int br = 0; br < 2; ++br) {
      const float* p = Qb + (q0 + qt * 16 + c) * D + br * 32 + 8 * g;
      float4 f0 = *(const float4*)p;
      float4 f1 = *(const float4*)(p + 4);
      bf16x8 v;
      v[0] = (__bf16)(f0.x * QSCALE); v[1] = (__bf16)(f0.y * QSCALE);
      v[2] = (__bf16)(f0.z * QSCALE); v[3] = (__bf16)(f0.w * QSCALE);
      v[4] = (__bf16)(f1.x * QSCALE); v[5] = (__bf16)(f1.y * QSCALE);
      v[6] = (__bf16)(f1.z * QSCALE); v[7] = (__bf16)(f1.w * QSCALE);
      bq[qt][br] = v;
    }

  f32x4 acc[2][2][4];
#pragma unroll
  for (int qt = 0; qt < 2; ++qt)
#pragma unroll
    for (int br = 0; br < 2; ++br)
#pragma unroll
      for (int dt = 0; dt < 4; ++dt)
        acc[qt][br][dt] = (f32x4){0.f, 0.f, 0.f, 0.f};
  float rsum[2][2] = {{0.f, 0.f}, {0.f, 0.f}};

#define LOADK(ak, ch) do {                                             \
    const __bf16* _p = Kbase + (size_t)(ch) * 2048;                    \
    ak[0][0] = *(const bf16x8*)_p;                                     \
    ak[0][1] = *(const bf16x8*)(_p + 512);                             \
    ak[1][0] = *(const bf16x8*)(_p + 1024);                            \
    ak[1][1] = *(const bf16x8*)(_p + 1536);                            \
  } while (0)

#define LOADV(av, ch) do {                                             \
    const __bf16* _p = Vbase + (size_t)(ch) * 2048;                    \
    _Pragma("unroll")                                                  \
    for (int dt = 0; dt < 4; ++dt)                                     \
      av[dt] = *(const bf16x8*)(_p + dt * 512);                        \
  } while (0)

  // K double-buffered (needed at step top); V single-buffered (reloaded
  // after its last use, one full step before the next PV needs it).
#define STEP(akc, akn, ch) do {                                           \
    LOADK(akn, ((ch) + 1) & 31);                                          \
    _Pragma("unroll")                                                     \
    for (int qt = 0; qt < 2; ++qt) {                                      \
      _Pragma("unroll")                                                   \
      for (int br = 0; br < 2; ++br) {                                    \
        f32x4 z = {0.f, 0.f, 0.f, 0.f};                                   \
        f32x4 sA = mfma16(akc[0][br], bq[qt][br], z);                     \
        f32x4 sB = mfma16(akc[1][br], bq[qt][br], z);                     \
        float pA[4], pB[4];                                               \
        _Pragma("unroll")                                                 \
        for (int r = 0; r < 4; ++r) {                                     \
          pA[r] = __builtin_amdgcn_exp2f(sA[r]);                          \
          pB[r] = __builtin_amdgcn_exp2f(sB[r]);                          \
        }                                                                 \
        rsum[qt][br] += (pA[0]+pA[1]+pA[2]+pA[3]) + (pB[0]+pB[1]+pB[2]+pB[3]); \
        uint2 uA; uA.x = cvtpk(pA[0], pA[1]); uA.y = cvtpk(pA[2], pA[3]); \
        uint2 uB; uB.x = cvtpk(pB[0], pB[1]); uB.y = cvtpk(pB[2], pB[3]); \
        Pl[w][qt][br][c][g]     = uA;                                     \
        Pl[w][qt][br][c][4 + g] = uB;                                     \
      }                                                                   \
      __builtin_amdgcn_sched_barrier(0);  /* DS in-order within wave */   \
      _Pragma("unroll")                                                   \
      for (int br = 0; br < 2; ++br) {                                    \
        uint2 lo = Pl[w][qt][br][c][2 * g];                               \
        uint2 hi = Pl[w][qt][br][c][2 * g + 1];                           \
        uint4 u = make_uint4(lo.x, lo.y, hi.x, hi.y);                     \
        bf16x8 bp = __builtin_bit_cast(bf16x8, u);                        \
        _Pragma("unroll")                                                 \
        for (int dt = 0; dt < 4; ++dt)                                    \
          acc[qt][br][dt] = mfma16(av[dt], bp, acc[qt][br][dt]);          \
      }                                                                   \
      __builtin_amdgcn_sched_barrier(0);  /* reads before next writes */  \
    }                                                                     \
    LOADV(av, ((ch) + 1) & 31);                                           \
  } while (0)

  bf16x8 k0[2][2], k1[2][2], av[4];
  LOADK(k0, 0);
  LOADV(av, 0);

#pragma unroll 1
  for (int ch = 0; ch < 32; ch += 2) {
    STEP(k0, k1, ch);
    STEP(k1, k0, ch + 1);
  }
#undef STEP
#undef LOADV
#undef LOADK

  // ---- merge kv-halves + epilogue, two qt rounds ----
#pragma unroll
  for (int qt = 0; qt < 2; ++qt) {
    float rs1 = rsum[qt][0], rs2 = rsum[qt][1];
    rs1 += __shfl_xor(rs1, 16); rs1 += __shfl_xor(rs1, 32);
    rs2 += __shfl_xor(rs2, 16); rs2 += __shfl_xor(rs2, 32);

    if (h == 1) {   // upper half publishes partials
#pragma unroll
      for (int br = 0; br < 2; ++br)
#pragma unroll
        for (int dt = 0; dt < 4; ++dt)
          Macc[ws][br][dt][lane] = acc[qt][br][dt];
      Mrs[ws][0][lane] = rs1;
      Mrs[ws][1][lane] = rs2;
    }
    __syncthreads();

    if (h == 0) {   // lower half merges, normalizes, LayerNorms, stores
      f32x4 a1[4], a2[4];
#pragma unroll
      for (int dt = 0; dt < 4; ++dt) {
        a1[dt] = acc[qt][0][dt] + Macc[ws][0][dt][lane];
        a2[dt] = acc[qt][1][dt] + Macc[ws][1][dt][lane];
      }
      const float t1 = rs1 + Mrs[ws][0][lane];
      const float t2 = rs2 + Mrs[ws][1][lane];
      const float inv1 = 1.0f / t1;
      const float inv2 = lam / t2;

      float vals[16];
      float sum = 0.f, sq = 0.f;
#pragma unroll
      for (int dt = 0; dt < 4; ++dt)
#pragma unroll
        for (int r = 0; r < 4; ++r) {
          float x = a1[dt][r] * inv1 - a2[dt][r] * inv2;
          vals[dt * 4 + r] = x;
          sum += x; sq += x * x;
        }
      sum += __shfl_xor(sum, 16); sum += __shfl_xor(sum, 32);
      sq  += __shfl_xor(sq, 16);  sq  += __shfl_xor(sq, 32);
      const float mean = sum * (1.0f / 64.0f);
      const float var  = sq * (1.0f / 64.0f) - mean * mean;
      const float rstd = rsqrtf(var + 1e-5f) * 0.2f;   // * (1 - LAMBDA_INIT)

      float* op = OUT + (size_t)bh * S * D + (size_t)(q0 + qt * 16 + c) * D;
#pragma unroll
      for (int dt = 0; dt < 4; ++dt) {
        float4 o;
        o.x = (vals[dt * 4 + 0] - mean) * rstd;
        o.y = (vals[dt * 4 + 1] - mean) * rstd;
        o.z = (vals[dt * 4 + 2] - mean) * rstd;
        o.w = (vals[dt * 4 + 3] - mean) * rstd;
        *(float4*)(op + 16 * dt + 4 * g) = o;
      }
    }
    __syncthreads();   // h==0 reads done before next round's publish
  }
}

extern "C" void kernel_launch(void* const* d_in, const int* in_sizes, int n_in,
                              void* d_out, int out_size, void* d_ws, size_t ws_size,
                              hipStream_t stream) {
  (void)in_sizes; (void)n_in; (void)out_size; (void)ws_size;
  const float* q  = (const float*)d_in[0];
  const float* k  = (const float*)d_in[1];
  const float* v  = (const float*)d_in[2];
  const float* lp = (const float*)d_in[3];
  float* out = (float*)d_out;

  __bf16* ks = (__bf16*)d_ws;                              // 8 MiB
  __bf16* vs = (__bf16*)((char*)d_ws + (8u << 20));        // 8 MiB

  kpack<<<dim3(2048), dim3(256), 0, stream>>>(k, ks);
  vpack<<<dim3(1024), dim3(256), 0, stream>>>(v, vs);
  diffattn<<<dim3(1024), dim3(256), 0, stream>>>(q, ks, vs, lp, out);
}

// Round 10
// 75.996 us; speedup vs baseline: 1.1246x; 1.1246x over previous
//
#include <hip/hip_runtime.h>

typedef __bf16 bf16x8 __attribute__((ext_vector_type(8)));
typedef float f32x4 __attribute__((ext_vector_type(4)));

static __device__ __forceinline__ f32x4 mfma16(bf16x8 a, bf16x8 b, f32x4 c) {
  return __builtin_amdgcn_mfma_f32_16x16x32_bf16(a, b, c, 0, 0, 0);
}
static __device__ __forceinline__ unsigned cvtpk(float lo, float hi) {
  unsigned r;
  asm("v_cvt_pk_bf16_f32 %0, %1, %2" : "=v"(r) : "v"(lo), "v"(hi));
  return r;
}

// ---- pre-pass 1: K fp32 -> bf16 packed in MFMA-fragment order ----
// KS[bh][ch][t2*2+br][g][c][j] : 1KB blocks; a wave's fragment load is one
// contiguous 1KB region (lane (c,g) reads 16B at g*256 + c*16).
__global__ __launch_bounds__(256)
void kpack(const float* __restrict__ K, __bf16* __restrict__ KS) {
  const int bh = blockIdx.x >> 6, ch = blockIdx.x & 63;
  const int t = threadIdx.x;
  const int t2 = t >> 7, br = (t >> 6) & 1, g = (t >> 4) & 3, c = t & 15;
  const float* src = K + ((size_t)bh * 2048 + ch * 32 + t2 * 16 + c) * 64 + br * 32 + g * 8;
  float4 f0 = *(const float4*)src;
  float4 f1 = *(const float4*)(src + 4);
  bf16x8 v;
  v[0] = (__bf16)f0.x; v[1] = (__bf16)f0.y; v[2] = (__bf16)f0.z; v[3] = (__bf16)f0.w;
  v[4] = (__bf16)f1.x; v[5] = (__bf16)f1.y; v[6] = (__bf16)f1.z; v[7] = (__bf16)f1.w;
  *(bf16x8*)(KS + (size_t)bh * 131072 + ch * 2048 + t * 8) = v;   // fully coalesced
}

// ---- pre-pass 2: V fp32 [bh][s][64] -> V^T bf16 packed fragment order ----
// VS[bh][ch][dt][g][c][j] = V[bh][ch*32+8g+j][16dt+c] : 1KB blocks.
__global__ __launch_bounds__(256)
void vpack(const float* __restrict__ V, __bf16* __restrict__ VS) {
  __shared__ float tile[64][65];
  const int bh = blockIdx.x >> 5;
  const int s0 = (blockIdx.x & 31) * 64;
  const int t = threadIdx.x;
  const float* Vb = V + (size_t)bh * 2048 * 64;
#pragma unroll
  for (int i = 0; i < 4; ++i) {
    const int r = i * 16 + (t >> 4);
    const int c4 = (t & 15) * 4;
    float4 v = *(const float4*)(Vb + (s0 + r) * 64 + c4);
    tile[r][c4] = v.x; tile[r][c4 + 1] = v.y;
    tile[r][c4 + 2] = v.z; tile[r][c4 + 3] = v.w;
  }
  __syncthreads();
  const int dt = t >> 6, g = (t >> 4) & 3, c = t & 15;
#pragma unroll
  for (int hh = 0; hh < 2; ++hh) {
    const int ch = (blockIdx.x & 31) * 2 + hh;
    bf16x8 v;
#pragma unroll
    for (int j = 0; j < 8; ++j) v[j] = (__bf16)tile[hh * 32 + 8 * g + j][16 * dt + c];
    *(bf16x8*)(VS + (size_t)bh * 131072 + ch * 2048 + dt * 512 + g * 128 + c * 8) = v;
  }
}

// ---- main: wide-phase swapped-operand flash diff-attention ----
// R10 vs R7: (a) ONE write->read sync per step (phase A = QK+exp+pack for
// BOTH qt -> 8 overlapping MFMA/exp chains; phase B = readP+PV for both qt,
// 20 back-to-back MFMAs) instead of 4 sync points; (b) softmax denominator
// via an all-ones 5th PV A-tile (P dot 1 = rowsum) -> no serial rsum adds in
// the exp chain and no epilogue shuffle-reduces. Base geometry = verified R7.
__global__ __launch_bounds__(256, 2)
void diffattn(const float* __restrict__ Q, const __bf16* __restrict__ KS,
              const __bf16* __restrict__ VS, const float* __restrict__ LP,
              float* __restrict__ OUT) {
  constexpr int S = 2048, D = 64;
  constexpr float QSCALE = 0.17677669529663687f * 1.4426950408889634f;

  __shared__ __align__(16) uint2 Pl[4][2][2][16][10];   // [w][qt][br][q][kv] 20480B

  const int raw = blockIdx.x;
  const int wg  = (raw & 7) * 64 + (raw >> 3);   // XCD swizzle (512 % 8 == 0)
  const int bh  = wg >> 4;
  const int qb  = wg & 15;
  const float lam = LP[bh & 15];

  const int tid  = threadIdx.x;
  const int w    = tid >> 6;
  const int lane = tid & 63;
  const int c    = lane & 15;
  const int g    = lane >> 4;
  const int q0   = qb * 128 + w * 32;            // 32 q rows per wave

  const float*  Qb    = Q  + (size_t)bh * S * D;
  const __bf16* Kbase = KS + (size_t)bh * 131072 + g * 128 + c * 8;
  const __bf16* Vbase = VS + (size_t)bh * 131072 + g * 128 + c * 8;

  // all-ones A-fragment: PV with this tile computes P-rowsums (softmax denom)
  bf16x8 aones;
  {
    uint4 u = make_uint4(0x3F803F80u, 0x3F803F80u, 0x3F803F80u, 0x3F803F80u);
    aones = __builtin_bit_cast(bf16x8, u);
  }

  // Q fragments: bq[qt][br], B[k = br*32+8g+j][n = c]
  bf16x8 bq[2][2];
#pragma unroll
  for (int qt = 0; qt < 2; ++qt)
#pragma unroll
    for (int br = 0; br < 2; ++br) {
      const float* p = Qb + (q0 + qt * 16 + c) * D + br * 32 + 8 * g;
      float4 f0 = *(const float4*)p;
      float4 f1 = *(const float4*)(p + 4);
      bf16x8 v;
      v[0] = (__bf16)(f0.x * QSCALE); v[1] = (__bf16)(f0.y * QSCALE);
      v[2] = (__bf16)(f0.z * QSCALE); v[3] = (__bf16)(f0.w * QSCALE);
      v[4] = (__bf16)(f1.x * QSCALE); v[5] = (__bf16)(f1.y * QSCALE);
      v[6] = (__bf16)(f1.z * QSCALE); v[7] = (__bf16)(f1.w * QSCALE);
      bq[qt][br] = v;
    }

  f32x4 acc[2][2][5];   // [qt][br][dt]; dt==4 is the ones-row (rowsum)
#pragma unroll
  for (int qt = 0; qt < 2; ++qt)
#pragma unroll
    for (int br = 0; br < 2; ++br)
#pragma unroll
      for (int dt = 0; dt < 5; ++dt)
        acc[qt][br][dt] = (f32x4){0.f, 0.f, 0.f, 0.f};

#define LOADK(ak, ch) do {                                             \
    const __bf16* _p = Kbase + (size_t)(ch) * 2048;                    \
    ak[0][0] = *(const bf16x8*)_p;                                     \
    ak[0][1] = *(const bf16x8*)(_p + 512);                             \
    ak[1][0] = *(const bf16x8*)(_p + 1024);                            \
    ak[1][1] = *(const bf16x8*)(_p + 1536);                            \
  } while (0)

#define LOADV(av, ch) do {                                             \
    const __bf16* _p = Vbase + (size_t)(ch) * 2048;                    \
    _Pragma("unroll")                                                  \
    for (int dt = 0; dt < 4; ++dt)                                     \
      av[dt] = *(const bf16x8*)(_p + dt * 512);                        \
  } while (0)

#define STEP(akc, akn, avc, avn, ch) do {                                 \
    LOADK(akn, ((ch) + 1) & 63);                                          \
    LOADV(avn, ((ch) + 1) & 63);                                          \
    /* phase A: QK + exp + pack + write, BOTH qt (8 independent chains) */ \
    _Pragma("unroll")                                                     \
    for (int qt = 0; qt < 2; ++qt)                                        \
      _Pragma("unroll")                                                   \
      for (int br = 0; br < 2; ++br) {                                    \
        f32x4 z = {0.f, 0.f, 0.f, 0.f};                                   \
        f32x4 sA = mfma16(akc[0][br], bq[qt][br], z);                     \
        f32x4 sB = mfma16(akc[1][br], bq[qt][br], z);                     \
        float pA[4], pB[4];                                               \
        _Pragma("unroll")                                                 \
        for (int r = 0; r < 4; ++r) {                                     \
          pA[r] = __builtin_amdgcn_exp2f(sA[r]);                          \
          pB[r] = __builtin_amdgcn_exp2f(sB[r]);                          \
        }                                                                 \
        uint2 uA; uA.x = cvtpk(pA[0], pA[1]); uA.y = cvtpk(pA[2], pA[3]); \
        uint2 uB; uB.x = cvtpk(pB[0], pB[1]); uB.y = cvtpk(pB[2], pB[3]); \
        Pl[w][qt][br][c][g]     = uA;                                     \
        Pl[w][qt][br][c][4 + g] = uB;                                     \
      }                                                                   \
    __builtin_amdgcn_sched_barrier(0);  /* single write->read sync */     \
    /* phase B: read P + PV (20 MFMAs incl. ones-row), BOTH qt */         \
    _Pragma("unroll")                                                     \
    for (int qt = 0; qt < 2; ++qt)                                        \
      _Pragma("unroll")                                                   \
      for (int br = 0; br < 2; ++br) {                                    \
        uint2 lo = Pl[w][qt][br][c][2 * g];                               \
        uint2 hi = Pl[w][qt][br][c][2 * g + 1];                           \
        uint4 u = make_uint4(lo.x, lo.y, hi.x, hi.y);                     \
        bf16x8 bp = __builtin_bit_cast(bf16x8, u);                        \
        _Pragma("unroll")                                                 \
        for (int dt = 0; dt < 4; ++dt)                                    \
          acc[qt][br][dt] = mfma16(avc[dt], bp, acc[qt][br][dt]);         \
        acc[qt][br][4] = mfma16(aones, bp, acc[qt][br][4]);               \
      }                                                                   \
    __builtin_amdgcn_sched_barrier(0);  /* reads before next step writes */ \
  } while (0)

  bf16x8 k0[2][2], k1[2][2], v0[4], v1[4];
  LOADK(k0, 0);
  LOADV(v0, 0);

#pragma unroll 1
  for (int ch = 0; ch < 64; ch += 2) {
    STEP(k0, k1, v0, v1, ch);
    STEP(k1, k0, v1, v0, ch + 1);
  }
#undef STEP
#undef LOADV
#undef LOADK

  // ---- epilogue: denominators from ones-row, combine, LayerNorm, store ----
#pragma unroll
  for (int qt = 0; qt < 2; ++qt) {
    const float inv1 = 1.0f / acc[qt][0][4][0];        // rowsum branch 1
    const float inv2 = lam / acc[qt][1][4][0];         // rowsum branch 2

    float vals[16];
    float sum = 0.f, sq = 0.f;
#pragma unroll
    for (int dt = 0; dt < 4; ++dt)
#pragma unroll
      for (int r = 0; r < 4; ++r) {
        float x = acc[qt][0][dt][r] * inv1 - acc[qt][1][dt][r] * inv2;
        vals[dt * 4 + r] = x;
        sum += x; sq += x * x;
      }
    sum += __shfl_xor(sum, 16); sum += __shfl_xor(sum, 32);
    sq  += __shfl_xor(sq, 16);  sq  += __shfl_xor(sq, 32);
    const float mean = sum * (1.0f / 64.0f);
    const float var  = sq * (1.0f / 64.0f) - mean * mean;
    const float rstd = rsqrtf(var + 1e-5f) * 0.2f;   // * (1 - LAMBDA_INIT)

    float* op = OUT + (size_t)bh * S * D + (size_t)(q0 + qt * 16 + c) * D;
#pragma unroll
    for (int dt = 0; dt < 4; ++dt) {
      float4 o;
      o.x = (vals[dt * 4 + 0] - mean) * rstd;
      o.y = (vals[dt * 4 + 1] - mean) * rstd;
      o.z = (vals[dt * 4 + 2] - mean) * rstd;
      o.w = (vals[dt * 4 + 3] - mean) * rstd;
      *(float4*)(op + 16 * dt + 4 * g) = o;
    }
  }
}

extern "C" void kernel_launch(void* const* d_in, const int* in_sizes, int n_in,
                              void* d_out, int out_size, void* d_ws, size_t ws_size,
                              hipStream_t stream) {
  (void)in_sizes; (void)n_in; (void)out_size; (void)ws_size;
  const float* q  = (const float*)d_in[0];
  const float* k  = (const float*)d_in[1];
  const float* v  = (const float*)d_in[2];
  const float* lp = (const float*)d_in[3];
  float* out = (float*)d_out;

  __bf16* ks = (__bf16*)d_ws;                              // 8 MiB
  __bf16* vs = (__bf16*)((char*)d_ws + (8u << 20));        // 8 MiB

  kpack<<<dim3(2048), dim3(256), 0, stream>>>(k, ks);
  vpack<<<dim3(1024), dim3(256), 0, stream>>>(v, vs);
  diffattn<<<dim3(512), dim3(256), 0, stream>>>(q, ks, vs, lp, out);
}